// Round 5
// baseline (488.843 us; speedup 1.0000x reference)
//
#include <hip/hip_runtime.h>

#define BATCH  4096
#define HIDDEN 2048
#define INPUT  2048
#define KDIM   4096   // INPUT + HIDDEN (fused K)
#define NDIM   8192   // 4 * HIDDEN (fused gate dim), gate-interleaved: n' = 4*j + g
#define BM 256
#define BN 256
#define BK 64
#define NT (KDIM / BK)   // 64 K-tiles

typedef __attribute__((ext_vector_type(8))) short short8;
typedef __attribute__((ext_vector_type(4))) float float4v;

// ---------- helpers ----------

__device__ __forceinline__ unsigned short f2bf(float f) {
    union { float f; unsigned u; } v; v.f = f;
    unsigned r = v.u + 0x7FFFu + ((v.u >> 16) & 1u);   // round-to-nearest-even
    return (unsigned short)(r >> 16);
}

__device__ __forceinline__ void gl2lds16(const unsigned short* g, unsigned short* l) {
    __builtin_amdgcn_global_load_lds(
        (const __attribute__((address_space(1))) unsigned int*)g,
        (__attribute__((address_space(3))) unsigned int*)l,
        16, 0, 0);
}

__device__ __forceinline__ float sigm(float x) {
    return 1.0f / (1.0f + __expf(-x));
}
__device__ __forceinline__ float tanh_fast(float x) {
    return 2.0f / (1.0f + __expf(-2.0f * x)) - 1.0f;
}

// raw barrier with compiler memory fence (no vmcnt/lgkmcnt drain — loads stay in flight)
__device__ __forceinline__ void fence_bar() {
    asm volatile("" ::: "memory");
    __builtin_amdgcn_s_barrier();
    asm volatile("" ::: "memory");
}

// ---------- kernel 1: pack [x | h] -> bf16, row-major K-contiguous ----------

__global__ void pack_x_kernel(const float* __restrict__ x, const float* __restrict__ h,
                              unsigned short* __restrict__ Xb) {
    int idx = blockIdx.x * 256 + threadIdx.x;   // one 8-element group per thread
    int b  = idx >> 9;                          // 512 groups per row (4096/8)
    int ko = idx & 511;
    const float* src = (ko < 256) ? (x + (size_t)b * INPUT  + (size_t)ko * 8)
                                  : (h + (size_t)b * HIDDEN + (size_t)(ko - 256) * 8);
    float4 v0 = *(const float4*)(src);
    float4 v1 = *(const float4*)(src + 4);
    union { unsigned short us[8]; uint4 v; } o;
    o.us[0] = f2bf(v0.x); o.us[1] = f2bf(v0.y); o.us[2] = f2bf(v0.z); o.us[3] = f2bf(v0.w);
    o.us[4] = f2bf(v1.x); o.us[5] = f2bf(v1.y); o.us[6] = f2bf(v1.z); o.us[7] = f2bf(v1.w);
    *(uint4*)(Xb + (size_t)b * KDIM + (size_t)ko * 8) = o.v;
}

// ---------- kernel 2: pack/transpose W' -> bf16 B^T, GATE-INTERLEAVED ----------

__global__ void pack_w_kernel(const float* __restrict__ w_ih, const float* __restrict__ w_hh,
                              unsigned short* __restrict__ Wt) {
    __shared__ unsigned short tile[32][136];
    const int k0 = blockIdx.x * 128;
    const int j0 = blockIdx.y * 32;
    const int g  = blockIdx.z;
    const float* src = (k0 < INPUT)
        ? (w_ih + (size_t)g * INPUT  * HIDDEN + (size_t)k0 * HIDDEN + j0)
        : (w_hh + (size_t)g * HIDDEN * HIDDEN + (size_t)(k0 - INPUT) * HIDDEN + j0);

    const int tid = threadIdx.x;
    const int jl  = (tid & 7) * 4;       // j within tile (0,4,...,28)
    const int kl  = (tid >> 3) * 2;      // k within half-tile (0..62, even)
#pragma unroll
    for (int p = 0; p < 2; ++p) {
        const int k = kl + p * 64;
        float4 v0 = *(const float4*)(src + (size_t)k * HIDDEN + jl);
        float4 v1 = *(const float4*)(src + (size_t)(k + 1) * HIDDEN + jl);
        unsigned p0 = (unsigned)f2bf(v0.x) | ((unsigned)f2bf(v1.x) << 16);
        unsigned p1 = (unsigned)f2bf(v0.y) | ((unsigned)f2bf(v1.y) << 16);
        unsigned p2 = (unsigned)f2bf(v0.z) | ((unsigned)f2bf(v1.z) << 16);
        unsigned p3 = (unsigned)f2bf(v0.w) | ((unsigned)f2bf(v1.w) << 16);
        *(unsigned*)&tile[jl + 0][kl + p * 64] = p0;
        *(unsigned*)&tile[jl + 1][kl + p * 64] = p1;
        *(unsigned*)&tile[jl + 2][kl + p * 64] = p2;
        *(unsigned*)&tile[jl + 3][kl + p * 64] = p3;
    }
    __syncthreads();

#pragma unroll
    for (int p = 0; p < 2; ++p) {
        const int cch = tid + p * 256;
        const int j   = cch >> 4;
        const int k8  = cch & 15;
        uint4 v = *(const uint4*)&tile[j][k8 * 8];
        *(uint4*)(Wt + (size_t)(4 * (j0 + j) + g) * KDIM + k0 + k8 * 8) = v;
    }
}

// ---------- kernel 3: 256x256 bf16 MFMA GEMM, 2-barrier/K-tile + fused LSTM epilogue ----------
// 512 threads = 8 waves (2M x 4N); per-wave output 128x64; BK=64, dbuf LDS 128 KiB.
// Only 2 barriers per K-tile: entry (vmcnt(8) publishes all waves' staged data) and
// trailing (protects old-cur from next tile's stages). Waves drift within a tile so
// ds_read and MFMA overlap across waves. XOR-swizzled LDS (T2), counted vmcnt (T4),
// setprio around MFMA (T5), bijective XCD-chunked block swizzle (T1, 512%8==0).

__global__ __launch_bounds__(512, 1)
void gemm_kernel(const unsigned short* __restrict__ A,
                 const unsigned short* __restrict__ B,
                 const float* __restrict__ c,
                 const float* __restrict__ b_ih,
                 const float* __restrict__ b_hh,
                 float* __restrict__ out) {
    extern __shared__ unsigned short lds[];
    unsigned short* cA = lds;
    unsigned short* nA = lds + 16384;
    unsigned short* cB = lds + 32768;
    unsigned short* nB = lds + 49152;

    const int tid  = threadIdx.x;
    const int wid  = tid >> 6;
    const int lane = tid & 63;
    const int ln   = lane & 15;
    const int kq   = lane >> 4;              // 0..3
    const int wmr  = (wid >> 2) * 128;       // wave row origin: 0 or 128
    const int wnr  = (wid & 3) * 64;         // wave col origin: 0,64,128,192

    // ---- T1: bijective XCD-chunked swizzle (nwg = 512, 512 % 8 == 0) ----
    const int nwgx = NDIM / BN;              // 32
    const int L    = blockIdx.y * nwgx + blockIdx.x;
    const int cpx  = (nwgx * (BATCH / BM)) >> 3;   // 64 blocks per XCD chunk
    const int Ls   = (L & 7) * cpx + (L >> 3);
    const int m0   = (Ls / nwgx) * BM;
    const int n0   = (Ls % nwgx) * BN;

    // ---- staging addresses ----
    const int srow  = tid >> 3;
    const int scol8 = (tid & 7) ^ (srow & 7);
    const unsigned short* gA[4];
    const unsigned short* gB[4];
#pragma unroll
    for (int cN = 0; cN < 4; ++cN) {
        gA[cN] = A + (size_t)(m0 + cN * 64 + srow) * KDIM + scol8 * 8;
        gB[cN] = B + (size_t)(n0 + cN * 64 + srow) * KDIM + scol8 * 8;
    }
    const int dOff = tid * 8;   // ushort units; + cN*4096

    // ---- fragment read offsets (read-side swizzle) ----
    const int abase = (wmr + ln) * 64;
    const int bbase = (wnr + ln) * 64;
    const int sk0 = ((0 + kq) ^ (ln & 7)) * 8;
    const int sk1 = ((4 + kq) ^ (ln & 7)) * 8;

    float4v acc[8][4];
#pragma unroll
    for (int i = 0; i < 8; ++i)
#pragma unroll
        for (int j = 0; j < 4; ++j)
            acc[i][j] = (float4v){0.f, 0.f, 0.f, 0.f};

#define STAGE_A(cN) gl2lds16(gA[cN] + konext, nA + (cN) * 4096 + dOff)
#define STAGE_B(cN) gl2lds16(gB[cN] + konext, nB + (cN) * 4096 + dOff)

    // ---- prologue: stage tile 0 into current buffers ----
    {
#pragma unroll
        for (int cN = 0; cN < 4; ++cN) gl2lds16(gB[cN], cB + cN * 4096 + dOff);
#pragma unroll
        for (int cN = 0; cN < 4; ++cN) gl2lds16(gA[cN], cA + cN * 4096 + dOff);
    }

    short8 bf[4][2];   // B fragments, held for the whole K-tile

    for (int T = 0; T < NT; ++T) {
        const bool last = (T == NT - 1);
        const int konext = (T + 1) * BK;

        // ---- burst-issue next tile into free buffer, counted wait for current ----
        if (!last) {
            STAGE_B(0); STAGE_B(1); STAGE_B(2); STAGE_B(3);
            STAGE_A(0); STAGE_A(1); STAGE_A(2); STAGE_A(3);
            asm volatile("s_waitcnt vmcnt(8)" ::: "memory");
        } else {
            asm volatile("s_waitcnt vmcnt(0)" ::: "memory");
        }
        fence_bar();   // publishes ALL waves' staged data for cur (vmcnt is per-wave)

        // ---- whole tile: no intra-tile barriers; waves drift ----
#pragma unroll
        for (int ni = 0; ni < 4; ++ni) {
            bf[ni][0] = *(const short8*)(cB + bbase + ni * 1024 + sk0);
            bf[ni][1] = *(const short8*)(cB + bbase + ni * 1024 + sk1);
        }
#pragma unroll
        for (int ph = 0; ph < 4; ++ph) {
            short8 a00 = *(const short8*)(cA + abase + (2 * ph) * 1024 + sk0);
            short8 a01 = *(const short8*)(cA + abase + (2 * ph) * 1024 + sk1);
            short8 a10 = *(const short8*)(cA + abase + (2 * ph + 1) * 1024 + sk0);
            short8 a11 = *(const short8*)(cA + abase + (2 * ph + 1) * 1024 + sk1);
            __builtin_amdgcn_s_setprio(1);
#pragma unroll
            for (int ni = 0; ni < 4; ++ni)
                acc[2 * ph][ni] = __builtin_amdgcn_mfma_f32_16x16x32_bf16(a00, bf[ni][0], acc[2 * ph][ni], 0, 0, 0);
#pragma unroll
            for (int ni = 0; ni < 4; ++ni)
                acc[2 * ph + 1][ni] = __builtin_amdgcn_mfma_f32_16x16x32_bf16(a10, bf[ni][0], acc[2 * ph + 1][ni], 0, 0, 0);
#pragma unroll
            for (int ni = 0; ni < 4; ++ni)
                acc[2 * ph][ni] = __builtin_amdgcn_mfma_f32_16x16x32_bf16(a01, bf[ni][1], acc[2 * ph][ni], 0, 0, 0);
#pragma unroll
            for (int ni = 0; ni < 4; ++ni)
                acc[2 * ph + 1][ni] = __builtin_amdgcn_mfma_f32_16x16x32_bf16(a11, bf[ni][1], acc[2 * ph + 1][ni], 0, 0, 0);
            __builtin_amdgcn_s_setprio(0);
        }

        fence_bar();   // all waves done reading cur before anyone stages into it

        // swap buffers
        unsigned short* t0 = cA; cA = nA; nA = t0;
        unsigned short* t1 = cB; cB = nB; nB = t1;
    }
#undef STAGE_A
#undef STAGE_B

    // ---- fused epilogue ----
    // First transpose: quad xor 1/2 over gate regs -> lane qg holds gates g0..g3 of
    // (row = wmr+mi*16+kq*4+qg, jg = jb + 4*ni + tq). Second transpose: xor 4/8 over
    // (tq, ni) -> lane holds 4 CONSECUTIVE jg => float4 c-load + float4 h/c stores.
    const int qg = lane & 3;
    const int tq = (lane & 15) >> 2;
    const int jb = (n0 >> 2) + (wnr >> 2);     // lane-uniform j base for this wave
    const size_t HB = (size_t)BATCH * HIDDEN;

    float bia[4][4];
#pragma unroll
    for (int ni = 0; ni < 4; ++ni) {
        const int jgq = jb + ni * 4 + tq;
        bia[ni][0] = b_ih[jgq]              + b_hh[jgq];
        bia[ni][1] = b_ih[HIDDEN + jgq]     + b_hh[HIDDEN + jgq];
        bia[ni][2] = b_ih[2 * HIDDEN + jgq] + b_hh[2 * HIDDEN + jgq];
        bia[ni][3] = b_ih[3 * HIDDEN + jgq] + b_hh[3 * HIDDEN + jgq];
    }

#pragma unroll
    for (int mi = 0; mi < 8; ++mi) {
        float fgv[4], pv[4], ogv[4];
#pragma unroll
        for (int ni = 0; ni < 4; ++ni) {
            float4v v = acc[mi][ni];
            // gate transpose: xor 1 then 2 within quad
            float t1 = __shfl_xor((qg & 1) ? v[0] : v[1], 1);
            float t2 = __shfl_xor((qg & 1) ? v[2] : v[3], 1);
            v[0] = (qg & 1) ? t1 : v[0];
            v[1] = (qg & 1) ? v[1] : t1;
            v[2] = (qg & 1) ? t2 : v[2];
            v[3] = (qg & 1) ? v[3] : t2;
            float t3 = __shfl_xor((qg & 2) ? v[0] : v[2], 2);
            float t4 = __shfl_xor((qg & 2) ? v[1] : v[3], 2);
            v[0] = (qg & 2) ? t3 : v[0];
            v[1] = (qg & 2) ? t4 : v[1];
            v[2] = (qg & 2) ? v[2] : t3;
            v[3] = (qg & 2) ? v[3] : t4;

            const float ig = sigm(v[0] + bia[ni][0]);
            const float fg = sigm(v[1] + bia[ni][1]);
            const float cg = tanh_fast(v[2] + bia[ni][2]);
            const float og = sigm(v[3] + bia[ni][3]);
            fgv[ni] = fg;
            pv[ni]  = ig * cg;
            ogv[ni] = og;
        }
        // second transpose: xor 4 then 8 over (tq, ni)
#define TRANS_T(a)                                                        \
        {                                                                 \
            float u1 = __shfl_xor((tq & 1) ? a[0] : a[1], 4);             \
            float u2 = __shfl_xor((tq & 1) ? a[2] : a[3], 4);             \
            a[0] = (tq & 1) ? u1 : a[0];                                  \
            a[1] = (tq & 1) ? a[1] : u1;                                  \
            a[2] = (tq & 1) ? u2 : a[2];                                  \
            a[3] = (tq & 1) ? a[3] : u2;                                  \
            float u3 = __shfl_xor((tq & 2) ? a[0] : a[2], 8);             \
            float u4 = __shfl_xor((tq & 2) ? a[1] : a[3], 8);             \
            a[0] = (tq & 2) ? u3 : a[0];                                  \
            a[2] = (tq & 2) ? a[2] : u3;                                  \
            a[1] = (tq & 2) ? u4 : a[1];                                  \
            a[3] = (tq & 2) ? a[3] : u4;                                  \
        }
        TRANS_T(fgv);
        TRANS_T(pv);
        TRANS_T(ogv);
#undef TRANS_T

        const int row = m0 + wmr + mi * 16 + kq * 4 + qg;
        const int jcol = jb + 4 * tq;
        const float4 cv = *(const float4*)(c + (size_t)row * HIDDEN + jcol);
        float4 hn4, cn4;
        {
            const float cn0 = fgv[0] * cv.x + pv[0];
            const float cn1 = fgv[1] * cv.y + pv[1];
            const float cn2 = fgv[2] * cv.z + pv[2];
            const float cn3 = fgv[3] * cv.w + pv[3];
            cn4.x = cn0; cn4.y = cn1; cn4.z = cn2; cn4.w = cn3;
            hn4.x = ogv[0] * tanh_fast(cn0);
            hn4.y = ogv[1] * tanh_fast(cn1);
            hn4.z = ogv[2] * tanh_fast(cn2);
            hn4.w = ogv[3] * tanh_fast(cn3);
        }
        *(float4*)(out + (size_t)row * HIDDEN + jcol)      = hn4;   // h_new
        *(float4*)(out + HB + (size_t)row * HIDDEN + jcol) = cn4;   // c_new
    }
}

// ---------- launcher ----------

extern "C" void kernel_launch(void* const* d_in, const int* in_sizes, int n_in,
                              void* d_out, int out_size, void* d_ws, size_t ws_size,
                              hipStream_t stream) {
    const float* x    = (const float*)d_in[0];
    const float* h    = (const float*)d_in[1];
    const float* c    = (const float*)d_in[2];
    const float* w_ih = (const float*)d_in[3];
    const float* w_hh = (const float*)d_in[4];
    const float* b_ih = (const float*)d_in[5];
    const float* b_hh = (const float*)d_in[6];
    float* out = (float*)d_out;

    const size_t XB_BYTES = (size_t)BATCH * KDIM * 2;   // 32 MB
    unsigned short* Xb = (unsigned short*)d_ws;
    unsigned short* Wt = (unsigned short*)((char*)d_ws + XB_BYTES);  // 64 MB

    hipLaunchKernelGGL(pack_x_kernel, dim3((size_t)BATCH * KDIM / 8 / 256), dim3(256), 0, stream,
                       x, h, Xb);
    hipLaunchKernelGGL(pack_w_kernel, dim3(KDIM / 128, HIDDEN / 32, 4), dim3(256), 0, stream,
                       w_ih, w_hh, Wt);
    hipLaunchKernelGGL(gemm_kernel, dim3(NDIM / BN, BATCH / BM), dim3(512), 131072, stream,
                       Xb, Wt, c, b_ih, b_hh, out);
}

// Round 6
// 482.517 us; speedup vs baseline: 1.0131x; 1.0131x over previous
//
#include <hip/hip_runtime.h>

#define BATCH  4096
#define HIDDEN 2048
#define INPUT  2048
#define KDIM   4096   // INPUT + HIDDEN (fused K)
#define NDIM   8192   // 4 * HIDDEN (fused gate dim), gate-interleaved: n' = 4*j + g
#define BM 256
#define BN 256
#define BK 64
#define NT (KDIM / BK)   // 64 K-tiles

typedef __attribute__((ext_vector_type(8))) short short8;
typedef __attribute__((ext_vector_type(4))) float float4v;

// ---------- helpers ----------

__device__ __forceinline__ unsigned short f2bf(float f) {
    union { float f; unsigned u; } v; v.f = f;
    unsigned r = v.u + 0x7FFFu + ((v.u >> 16) & 1u);   // round-to-nearest-even
    return (unsigned short)(r >> 16);
}

__device__ __forceinline__ void gl2lds16(const unsigned short* g, unsigned short* l) {
    __builtin_amdgcn_global_load_lds(
        (const __attribute__((address_space(1))) unsigned int*)g,
        (__attribute__((address_space(3))) unsigned int*)l,
        16, 0, 0);
}

__device__ __forceinline__ float sigm(float x) {
    return 1.0f / (1.0f + __expf(-x));
}
__device__ __forceinline__ float tanh_fast(float x) {
    return 2.0f / (1.0f + __expf(-2.0f * x)) - 1.0f;
}

// raw barrier with compiler memory fence (no vmcnt/lgkmcnt drain — loads stay in flight)
__device__ __forceinline__ void fence_bar() {
    asm volatile("" ::: "memory");
    __builtin_amdgcn_s_barrier();
    asm volatile("" ::: "memory");
}

// ---------- kernel 1: pack [x | h] -> bf16, row-major K-contiguous ----------

__global__ void pack_x_kernel(const float* __restrict__ x, const float* __restrict__ h,
                              unsigned short* __restrict__ Xb) {
    int idx = blockIdx.x * 256 + threadIdx.x;   // one 8-element group per thread
    int b  = idx >> 9;                          // 512 groups per row (4096/8)
    int ko = idx & 511;
    const float* src = (ko < 256) ? (x + (size_t)b * INPUT  + (size_t)ko * 8)
                                  : (h + (size_t)b * HIDDEN + (size_t)(ko - 256) * 8);
    float4 v0 = *(const float4*)(src);
    float4 v1 = *(const float4*)(src + 4);
    union { unsigned short us[8]; uint4 v; } o;
    o.us[0] = f2bf(v0.x); o.us[1] = f2bf(v0.y); o.us[2] = f2bf(v0.z); o.us[3] = f2bf(v0.w);
    o.us[4] = f2bf(v1.x); o.us[5] = f2bf(v1.y); o.us[6] = f2bf(v1.z); o.us[7] = f2bf(v1.w);
    *(uint4*)(Xb + (size_t)b * KDIM + (size_t)ko * 8) = o.v;
}

// ---------- kernel 2: pack/transpose W' -> bf16 B^T, GATE-INTERLEAVED ----------

__global__ void pack_w_kernel(const float* __restrict__ w_ih, const float* __restrict__ w_hh,
                              unsigned short* __restrict__ Wt) {
    __shared__ unsigned short tile[32][136];
    const int k0 = blockIdx.x * 128;
    const int j0 = blockIdx.y * 32;
    const int g  = blockIdx.z;
    const float* src = (k0 < INPUT)
        ? (w_ih + (size_t)g * INPUT  * HIDDEN + (size_t)k0 * HIDDEN + j0)
        : (w_hh + (size_t)g * HIDDEN * HIDDEN + (size_t)(k0 - INPUT) * HIDDEN + j0);

    const int tid = threadIdx.x;
    const int jl  = (tid & 7) * 4;       // j within tile (0,4,...,28)
    const int kl  = (tid >> 3) * 2;      // k within half-tile (0..62, even)
#pragma unroll
    for (int p = 0; p < 2; ++p) {
        const int k = kl + p * 64;
        float4 v0 = *(const float4*)(src + (size_t)k * HIDDEN + jl);
        float4 v1 = *(const float4*)(src + (size_t)(k + 1) * HIDDEN + jl);
        unsigned p0 = (unsigned)f2bf(v0.x) | ((unsigned)f2bf(v1.x) << 16);
        unsigned p1 = (unsigned)f2bf(v0.y) | ((unsigned)f2bf(v1.y) << 16);
        unsigned p2 = (unsigned)f2bf(v0.z) | ((unsigned)f2bf(v1.z) << 16);
        unsigned p3 = (unsigned)f2bf(v0.w) | ((unsigned)f2bf(v1.w) << 16);
        *(unsigned*)&tile[jl + 0][kl + p * 64] = p0;
        *(unsigned*)&tile[jl + 1][kl + p * 64] = p1;
        *(unsigned*)&tile[jl + 2][kl + p * 64] = p2;
        *(unsigned*)&tile[jl + 3][kl + p * 64] = p3;
    }
    __syncthreads();

#pragma unroll
    for (int p = 0; p < 2; ++p) {
        const int cch = tid + p * 256;
        const int j   = cch >> 4;
        const int k8  = cch & 15;
        uint4 v = *(const uint4*)&tile[j][k8 * 8];
        *(uint4*)(Wt + (size_t)(4 * (j0 + j) + g) * KDIM + k0 + k8 * 8) = v;
    }
}

// ---------- kernel 3: 256x256 bf16 MFMA GEMM, pipelined frag reads + fused LSTM epilogue ----------
// 512 threads = 8 waves (2M x 4N); per-wave output 128x64; BK=64, dbuf LDS 128 KiB.
// 2 barriers per K-tile. INTRA-WAVE SOFTWARE PIPELINE: phase p+1's A-frag ds_reads are
// issued BEFORE phase p's 16-MFMA cluster, so the compiler's fine-grained lgkmcnt leaves
// them in flight under the MFMAs -> LDS pipe and matrix pipe co-busy (round-5 model:
// zero-overlap sum 5550 cyc/tile matched measured 5460; this targets the overlap).
// XOR-swizzled LDS (T2, 0 conflicts), counted vmcnt(8) (T4), setprio (T5). No XCD
// swizzle (round-5: it tripled FETCH_SIZE; working set is L3-fit).

__global__ __launch_bounds__(512, 1)
void gemm_kernel(const unsigned short* __restrict__ A,
                 const unsigned short* __restrict__ B,
                 const float* __restrict__ c,
                 const float* __restrict__ b_ih,
                 const float* __restrict__ b_hh,
                 float* __restrict__ out) {
    extern __shared__ unsigned short lds[];
    unsigned short* cA = lds;
    unsigned short* nA = lds + 16384;
    unsigned short* cB = lds + 32768;
    unsigned short* nB = lds + 49152;

    const int tid  = threadIdx.x;
    const int wid  = tid >> 6;
    const int lane = tid & 63;
    const int ln   = lane & 15;
    const int kq   = lane >> 4;              // 0..3
    const int wmr  = (wid >> 2) * 128;       // wave row origin: 0 or 128
    const int wnr  = (wid & 3) * 64;         // wave col origin: 0,64,128,192
    const int m0   = blockIdx.y * BM;
    const int n0   = blockIdx.x * BN;

    // ---- staging addresses ----
    const int srow  = tid >> 3;
    const int scol8 = (tid & 7) ^ (srow & 7);
    const unsigned short* gA[4];
    const unsigned short* gB[4];
#pragma unroll
    for (int cN = 0; cN < 4; ++cN) {
        gA[cN] = A + (size_t)(m0 + cN * 64 + srow) * KDIM + scol8 * 8;
        gB[cN] = B + (size_t)(n0 + cN * 64 + srow) * KDIM + scol8 * 8;
    }
    const int dOff = tid * 8;   // ushort units; + cN*4096

    // ---- fragment read offsets (read-side swizzle) ----
    const int abase = (wmr + ln) * 64;
    const int bbase = (wnr + ln) * 64;
    const int sk0 = ((0 + kq) ^ (ln & 7)) * 8;
    const int sk1 = ((4 + kq) ^ (ln & 7)) * 8;

    float4v acc[8][4];
#pragma unroll
    for (int i = 0; i < 8; ++i)
#pragma unroll
        for (int j = 0; j < 4; ++j)
            acc[i][j] = (float4v){0.f, 0.f, 0.f, 0.f};

#define STAGE_A(cN) gl2lds16(gA[cN] + konext, nA + (cN) * 4096 + dOff)
#define STAGE_B(cN) gl2lds16(gB[cN] + konext, nB + (cN) * 4096 + dOff)
    // A-frag read: phase ph, part r (r0=row 2ph k-half0, r1=row 2ph k-half1,
    //                               r2=row 2ph+1 k-half0, r3=row 2ph+1 k-half1)
#define RD_A(ph, r) (*(const short8*)(cA + abase + (2 * (ph) + ((r) >> 1)) * 1024 \
                                      + (((r) & 1) ? sk1 : sk0)))

    // ---- prologue: stage tile 0 into current buffers ----
    {
#pragma unroll
        for (int cN = 0; cN < 4; ++cN) gl2lds16(gB[cN], cB + cN * 4096 + dOff);
#pragma unroll
        for (int cN = 0; cN < 4; ++cN) gl2lds16(gA[cN], cA + cN * 4096 + dOff);
    }

    short8 bfv[4][2];   // B fragments, held for the whole K-tile
    short8 afr[2][4];   // A fragments, double-buffered across phases

    for (int T = 0; T < NT; ++T) {
        const bool last = (T == NT - 1);
        const int konext = (T + 1) * BK;

        // ---- burst-issue next tile into free buffer, counted wait for current ----
        if (!last) {
            STAGE_B(0); STAGE_B(1); STAGE_B(2); STAGE_B(3);
            STAGE_A(0); STAGE_A(1); STAGE_A(2); STAGE_A(3);
            asm volatile("s_waitcnt vmcnt(8)" ::: "memory");
        } else {
            asm volatile("s_waitcnt vmcnt(0)" ::: "memory");
        }
        fence_bar();   // publishes ALL waves' staged data for cur (vmcnt is per-wave)

        // ---- tile compute: pipelined fragment reads ----
        // phase-0 A-frags first, then B-frags (first MFMA can start after ~6 reads)
#pragma unroll
        for (int r = 0; r < 4; ++r) afr[0][r] = RD_A(0, r);
#pragma unroll
        for (int ni = 0; ni < 4; ++ni) {
            bfv[ni][0] = *(const short8*)(cB + bbase + ni * 1024 + sk0);
            bfv[ni][1] = *(const short8*)(cB + bbase + ni * 1024 + sk1);
        }
#pragma unroll
        for (int ph = 0; ph < 4; ++ph) {
            const int cur = ph & 1;
            if (ph < 3) {   // issue NEXT phase's reads before this phase's MFMAs
#pragma unroll
                for (int r = 0; r < 4; ++r) afr[cur ^ 1][r] = RD_A(ph + 1, r);
            }
            __builtin_amdgcn_s_setprio(1);
#pragma unroll
            for (int ni = 0; ni < 4; ++ni)
                acc[2 * ph][ni] = __builtin_amdgcn_mfma_f32_16x16x32_bf16(
                    afr[cur][0], bfv[ni][0], acc[2 * ph][ni], 0, 0, 0);
#pragma unroll
            for (int ni = 0; ni < 4; ++ni)
                acc[2 * ph + 1][ni] = __builtin_amdgcn_mfma_f32_16x16x32_bf16(
                    afr[cur][2], bfv[ni][0], acc[2 * ph + 1][ni], 0, 0, 0);
#pragma unroll
            for (int ni = 0; ni < 4; ++ni)
                acc[2 * ph][ni] = __builtin_amdgcn_mfma_f32_16x16x32_bf16(
                    afr[cur][1], bfv[ni][1], acc[2 * ph][ni], 0, 0, 0);
#pragma unroll
            for (int ni = 0; ni < 4; ++ni)
                acc[2 * ph + 1][ni] = __builtin_amdgcn_mfma_f32_16x16x32_bf16(
                    afr[cur][3], bfv[ni][1], acc[2 * ph + 1][ni], 0, 0, 0);
            __builtin_amdgcn_s_setprio(0);
        }

        fence_bar();   // all waves done reading cur before anyone stages into it

        // swap buffers
        unsigned short* t0 = cA; cA = nA; nA = t0;
        unsigned short* t1 = cB; cB = nB; nB = t1;
    }
#undef STAGE_A
#undef STAGE_B
#undef RD_A

    // ---- fused epilogue ----
    // First transpose: quad xor 1/2 over gate regs -> lane qg holds gates g0..g3 of
    // (row = wmr+mi*16+kq*4+qg, jg = jb + 4*ni + tq). Second transpose: xor 4/8 over
    // (tq, ni) -> lane holds 4 CONSECUTIVE jg => float4 c-load + float4 h/c stores.
    const int qg = lane & 3;
    const int tq = (lane & 15) >> 2;
    const int jb = (n0 >> 2) + (wnr >> 2);     // lane-uniform j base for this wave
    const size_t HB = (size_t)BATCH * HIDDEN;

    float bia[4][4];
#pragma unroll
    for (int ni = 0; ni < 4; ++ni) {
        const int jgq = jb + ni * 4 + tq;
        bia[ni][0] = b_ih[jgq]              + b_hh[jgq];
        bia[ni][1] = b_ih[HIDDEN + jgq]     + b_hh[HIDDEN + jgq];
        bia[ni][2] = b_ih[2 * HIDDEN + jgq] + b_hh[2 * HIDDEN + jgq];
        bia[ni][3] = b_ih[3 * HIDDEN + jgq] + b_hh[3 * HIDDEN + jgq];
    }

#pragma unroll
    for (int mi = 0; mi < 8; ++mi) {
        float fgv[4], pv[4], ogv[4];
#pragma unroll
        for (int ni = 0; ni < 4; ++ni) {
            float4v v = acc[mi][ni];
            // gate transpose: xor 1 then 2 within quad
            float t1 = __shfl_xor((qg & 1) ? v[0] : v[1], 1);
            float t2 = __shfl_xor((qg & 1) ? v[2] : v[3], 1);
            v[0] = (qg & 1) ? t1 : v[0];
            v[1] = (qg & 1) ? v[1] : t1;
            v[2] = (qg & 1) ? t2 : v[2];
            v[3] = (qg & 1) ? v[3] : t2;
            float t3 = __shfl_xor((qg & 2) ? v[0] : v[2], 2);
            float t4 = __shfl_xor((qg & 2) ? v[1] : v[3], 2);
            v[0] = (qg & 2) ? t3 : v[0];
            v[1] = (qg & 2) ? t4 : v[1];
            v[2] = (qg & 2) ? v[2] : t3;
            v[3] = (qg & 2) ? v[3] : t4;

            const float ig = sigm(v[0] + bia[ni][0]);
            const float fg = sigm(v[1] + bia[ni][1]);
            const float cg = tanh_fast(v[2] + bia[ni][2]);
            const float og = sigm(v[3] + bia[ni][3]);
            fgv[ni] = fg;
            pv[ni]  = ig * cg;
            ogv[ni] = og;
        }
        // second transpose: xor 4 then 8 over (tq, ni)
#define TRANS_T(a)                                                        \
        {                                                                 \
            float u1 = __shfl_xor((tq & 1) ? a[0] : a[1], 4);             \
            float u2 = __shfl_xor((tq & 1) ? a[2] : a[3], 4);             \
            a[0] = (tq & 1) ? u1 : a[0];                                  \
            a[1] = (tq & 1) ? a[1] : u1;                                  \
            a[2] = (tq & 1) ? u2 : a[2];                                  \
            a[3] = (tq & 1) ? a[3] : u2;                                  \
            float u3 = __shfl_xor((tq & 2) ? a[0] : a[2], 8);             \
            float u4 = __shfl_xor((tq & 2) ? a[1] : a[3], 8);             \
            a[0] = (tq & 2) ? u3 : a[0];                                  \
            a[2] = (tq & 2) ? a[2] : u3;                                  \
            a[1] = (tq & 2) ? u4 : a[1];                                  \
            a[3] = (tq & 2) ? a[3] : u4;                                  \
        }
        TRANS_T(fgv);
        TRANS_T(pv);
        TRANS_T(ogv);
#undef TRANS_T

        const int row = m0 + wmr + mi * 16 + kq * 4 + qg;
        const int jcol = jb + 4 * tq;
        const float4 cv = *(const float4*)(c + (size_t)row * HIDDEN + jcol);
        float4 hn4, cn4;
        {
            const float cn0 = fgv[0] * cv.x + pv[0];
            const float cn1 = fgv[1] * cv.y + pv[1];
            const float cn2 = fgv[2] * cv.z + pv[2];
            const float cn3 = fgv[3] * cv.w + pv[3];
            cn4.x = cn0; cn4.y = cn1; cn4.z = cn2; cn4.w = cn3;
            hn4.x = ogv[0] * tanh_fast(cn0);
            hn4.y = ogv[1] * tanh_fast(cn1);
            hn4.z = ogv[2] * tanh_fast(cn2);
            hn4.w = ogv[3] * tanh_fast(cn3);
        }
        *(float4*)(out + (size_t)row * HIDDEN + jcol)      = hn4;   // h_new
        *(float4*)(out + HB + (size_t)row * HIDDEN + jcol) = cn4;   // c_new
    }
}

// ---------- launcher ----------

extern "C" void kernel_launch(void* const* d_in, const int* in_sizes, int n_in,
                              void* d_out, int out_size, void* d_ws, size_t ws_size,
                              hipStream_t stream) {
    const float* x    = (const float*)d_in[0];
    const float* h    = (const float*)d_in[1];
    const float* c    = (const float*)d_in[2];
    const float* w_ih = (const float*)d_in[3];
    const float* w_hh = (const float*)d_in[4];
    const float* b_ih = (const float*)d_in[5];
    const float* b_hh = (const float*)d_in[6];
    float* out = (float*)d_out;

    const size_t XB_BYTES = (size_t)BATCH * KDIM * 2;   // 32 MB
    unsigned short* Xb = (unsigned short*)d_ws;
    unsigned short* Wt = (unsigned short*)((char*)d_ws + XB_BYTES);  // 64 MB

    hipLaunchKernelGGL(pack_x_kernel, dim3((size_t)BATCH * KDIM / 8 / 256), dim3(256), 0, stream,
                       x, h, Xb);
    hipLaunchKernelGGL(pack_w_kernel, dim3(KDIM / 128, HIDDEN / 32, 4), dim3(256), 0, stream,
                       w_ih, w_hh, Wt);
    hipLaunchKernelGGL(gemm_kernel, dim3(NDIM / BN, BATCH / BM), dim3(512), 131072, stream,
                       Xb, Wt, c, b_ih, b_hh, out);
}